// Round 2
// baseline (132.829 us; speedup 1.0000x reference)
//
#include <hip/hip_runtime.h>

#define NUM_FIELDS 10
#define EMB 64
#define ROW 128            // 2 * EMB floats per embedding row
#define WAVES_PER_BLOCK 4  // 256 threads

// One wave per batch element. Each lane loads one float2 of the 128-float
// embedding row (row + 2*lane spans the whole row across 64 lanes):
//   lanes  0..31 -> dims [0,64)   = FM order-2 half (2 dims/lane)
//   lanes 32..63 -> dims [64,128) = ANOVA order-3 half (2 dims/lane)
// Power sums + Newton identities replace the cumsum DP:
//   e2 = (p1^2 - p2)/2,  e3 = (p1^3 - 3 p1 p2 + 2 p3)/6
__global__ __launch_bounds__(256) void fm_ho_kernel(
    const int* __restrict__ x, const int* __restrict__ offsets,
    const float* __restrict__ W_emb, const float* __restrict__ W_lin,
    const float* __restrict__ bias, float* __restrict__ out, int batch)
{
    const int lane = threadIdx.x & 63;
    const int wave = threadIdx.x >> 6;
    const int b = blockIdx.x * WAVES_PER_BLOCK + wave;
    if (b >= batch) return;

    // Wave-uniform index loads (same address across lanes -> HW broadcast).
    int ids[NUM_FIELDS];
#pragma unroll
    for (int f = 0; f < NUM_FIELDS; ++f)
        ids[f] = x[b * NUM_FIELDS + f] + offsets[f];

    const float2* __restrict__ W2 = (const float2*)W_emb;

    // Per-lane power sums over fields (x/y = the lane's two dims).
    float s1x = 0.f, s1y = 0.f, s2x = 0.f, s2y = 0.f, s3x = 0.f, s3y = 0.f;
#pragma unroll
    for (int f = 0; f < NUM_FIELDS; ++f) {
        // 32-bit index math: max id*64+lane = 180000*64+63 < 2^31
        float2 e = W2[(unsigned)ids[f] * (ROW / 2) + lane];
        s1x += e.x;               s1y += e.y;
        s2x = fmaf(e.x, e.x, s2x); s2y = fmaf(e.y, e.y, s2y);
        s3x = fmaf(e.x * e.x, e.x, s3x); s3y = fmaf(e.y * e.y, e.y, s3y);
    }

    float v;
    if (lane < 32) {
        // FM order-2: 0.5*(p1^2 - p2) per dim
        v = 0.5f * ((s1x * s1x - s2x) + (s1y * s1y - s2y));
    } else {
        // ANOVA order-3: (p1^3 - 3 p1 p2 + 2 p3)/6 per dim
        v = ((s1x * s1x * s1x - 3.f * s1x * s2x + 2.f * s3x)
           + (s1y * s1y * s1y - 3.f * s1y * s2y + 2.f * s3y)) * (1.f / 6.f);
    }

    // Linear term: lanes 0..9 each add one W_lin entry before the reduction.
    if (lane < NUM_FIELDS) v += W_lin[ids[lane]];

    // 64-lane butterfly reduction.
#pragma unroll
    for (int off = 32; off; off >>= 1)
        v += __shfl_xor(v, off, 64);

    if (lane == 0) {
        float y = v + bias[0];
        out[b] = y > 0.f ? y : 0.f;
    }
}

extern "C" void kernel_launch(void* const* d_in, const int* in_sizes, int n_in,
                              void* d_out, int out_size, void* d_ws, size_t ws_size,
                              hipStream_t stream) {
    const int*   x       = (const int*)d_in[0];
    const int*   offsets = (const int*)d_in[1];
    const float* W_emb   = (const float*)d_in[2];
    const float* W_lin   = (const float*)d_in[3];
    const float* bias    = (const float*)d_in[4];
    float*       out     = (float*)d_out;

    const int batch = in_sizes[0] / NUM_FIELDS; // 16384
    const int grid  = (batch + WAVES_PER_BLOCK - 1) / WAVES_PER_BLOCK;
    hipLaunchKernelGGL(fm_ho_kernel, dim3(grid), dim3(256), 0, stream,
                       x, offsets, W_emb, W_lin, bias, out, batch);
}